// Round 7
// baseline (823.377 us; speedup 1.0000x reference)
//
#include <hip/hip_runtime.h>

// Fused SIREN INR round 7. r6 structure (TOK=128, 512 thr, chunk-major LDS,
// fragment-ordered weights, 2-deep a-prefetch, b dbuf) with the layer GEMMs
// moved from 16x16x32 to 32x32x16 f16 MFMA:
//   - matrix-pipe ceiling 1955 -> 2178 TF (µbench m64/m23), ~11% more
//   - MFMA instruction count halves (256/wave/layer) -> issue-port relief
//   - same acc footprint (2x4 tiles x 16 f32 = 128), same 1KB a-bursts
// A-layout: row=lane&31, k=(lane>>5)*8+e (frag-ordered by convert kernel).
// C/D (verified m74/m101): col=lane&31, row=(reg&3)+8*(reg>>2)+4*(lane>>5)
// -> reg quads are 4 consecutive features -> packed f16x4 LDS writeback.
// Locked: 1x weight L2 traffic/CU, coalesced 1KB a-bursts, deep prefetch.

#define L_TOTAL 262144
#define TOK 128
#define THREADS 512
#define C_SC 4.77464829275686f  // 30/(2*pi)

typedef _Float16 f16x8 __attribute__((ext_vector_type(8)));
typedef _Float16 f16x4 __attribute__((ext_vector_type(4)));
typedef float    f32x4 __attribute__((ext_vector_type(4)));
typedef float    f32x16 __attribute__((ext_vector_type(16)));

#define N1 (512 * 256)                 // W_first elems
#define N2 (N1 + 5 * 512 * 512)        // + W_hidden
#define N3 (N2 + 16 * 512)             // + W_out padded to 16 rows
#define NBIAS 3072                     // 512 first + 5*512 hidden (pre-scaled)

// Fragment order for 32x32x16: dst[((mtile*KS + ks)*64 + lane)*8 + e] =
//   W[row = mtile*32 + (lane&31)][col = ks*16 + (lane>>5)*8 + e]
__global__ void convert_weights(const float* __restrict__ Wf,
                                const float* __restrict__ Wh,
                                const float* __restrict__ Wo,
                                const float* __restrict__ bf,
                                const float* __restrict__ bh,
                                _Float16* __restrict__ o,
                                float* __restrict__ biasC) {
  int i = blockIdx.x * blockDim.x + threadIdx.x;
  if (i < N3) {
    float v;
    if (i < N1) {                      // first layer: 512x256, KS=16
      const int blk = i >> 9, w = i & 511;
      const int lane = w >> 3, e = w & 7;
      const int mt = blk >> 4, ks = blk & 15;
      const int row = mt * 32 + (lane & 31);
      const int col = ks * 16 + (lane >> 5) * 8 + e;
      v = Wf[row * 256 + col];
    } else if (i < N2) {               // hidden: 5 x 512x512, KS=32
      int j = i - N1;
      const int l = j >> 18;
      j &= (1 << 18) - 1;
      const int blk = j >> 9, w = j & 511;
      const int lane = w >> 3, e = w & 7;
      const int mt = blk >> 5, ks = blk & 31;
      const int row = mt * 32 + (lane & 31);
      const int col = ks * 16 + (lane >> 5) * 8 + e;
      v = Wh[l * (512 * 512) + row * 512 + col];
    } else {                           // out layer: row-major, padded 16x512
      const int r = (i - N2) >> 9, c = (i - N2) & 511;
      v = (r < 3) ? Wo[r * 512 + c] : 0.0f;
    }
    o[i] = (_Float16)v;
  } else if (i < N3 + NBIAS) {
    int j = i - N3;
    biasC[j] = (j < 512 ? bf[j] : bh[j - 512]) * C_SC;
  }
}

// h LDS layout: elem addr = (chunk*128 + token)*8 + (f&7), chunk = f>>3.
__device__ __forceinline__ int h_elem(int chunk, int token) {
  return (chunk * 128 + token) * 8;
}

// One sine layer on 32x32x16: M=512 (8 waves x 2 mtiles of 32), N=128 tokens
// (4 ntiles of 32), KS k-steps of K=16. W fragment-ordered.
template <int KS>
__device__ __forceinline__ void sine_layer(const _Float16* __restrict__ W,
                                           const float* __restrict__ biasC,
                                           _Float16* hb, int lane, int m0t,
                                           int hl, int ln31) {
  f32x16 acc[2][4];
#pragma unroll
  for (int mt = 0; mt < 2; ++mt)
#pragma unroll
    for (int nt = 0; nt < 4; ++nt)
#pragma unroll
      for (int r = 0; r < 16; ++r) acc[mt][nt][r] = 0.f;

  // per-mtile fragment base: one contiguous 1KB burst per (mt, ks)
  const _Float16* wb[2];
#pragma unroll
  for (int mt = 0; mt < 2; ++mt)
    wb[mt] = &W[((m0t + mt) * KS) * 512 + lane * 8];

  f16x8 a[3][2], b[2][4];
#pragma unroll
  for (int mt = 0; mt < 2; ++mt) {
    a[0][mt] = *(const f16x8*)(wb[mt]);
    a[1][mt] = *(const f16x8*)(wb[mt] + 512);
  }
#pragma unroll
  for (int nt = 0; nt < 4; ++nt)
    b[0][nt] = *(const f16x8*)&hb[h_elem(hl, nt * 32 + ln31)];

#pragma unroll
  for (int ks = 0; ks < KS; ++ks) {
    const int cur = ks & 1;
    const int ai = ks % 3;
    if (ks + 1 < KS) {  // b-frags for next k-step under these MFMAs
#pragma unroll
      for (int nt = 0; nt < 4; ++nt)
        b[cur ^ 1][nt] =
            *(const f16x8*)&hb[h_elem((ks + 1) * 2 + hl, nt * 32 + ln31)];
    }
    if (ks + 2 < KS) {  // 2-deep a-prefetch
#pragma unroll
      for (int mt = 0; mt < 2; ++mt)
        a[(ks + 2) % 3][mt] = *(const f16x8*)(wb[mt] + (ks + 2) * 512);
    }
#pragma unroll
    for (int mt = 0; mt < 2; ++mt)
#pragma unroll
      for (int nt = 0; nt < 4; ++nt)
        acc[mt][nt] = __builtin_amdgcn_mfma_f32_32x32x16_f16(
            a[ai][mt], b[cur][nt], acc[mt][nt], 0, 0, 0);
  }
  __syncthreads();  // all reads of hb done before overwrite

  // C/D: col = ln31 (token), row = (reg&3) + 8*(reg>>2) + 4*hl
#pragma unroll
  for (int mt = 0; mt < 2; ++mt) {
#pragma unroll
    for (int q = 0; q < 4; ++q) {
      const int fb = (m0t + mt) * 32 + q * 8;   // quad feature base (mod 8 =0)
      const int ob = fb + hl * 4;               // 4 consecutive out-features
      const f32x4 bb = *(const f32x4*)&biasC[ob];
      const int wbase = (fb >> 3) * 1024 + hl * 4;
#pragma unroll
      for (int nt = 0; nt < 4; ++nt) {
        f16x4 hv;
#pragma unroll
        for (int r = 0; r < 4; ++r) {
          float pre = fmaf(acc[mt][nt][q * 4 + r], C_SC, bb[r]);  // revs
          hv[r] = (_Float16)__builtin_amdgcn_sinf(__builtin_amdgcn_fractf(pre));
        }
        *(f16x4*)&hb[wbase + (nt * 32 + ln31) * 8] = hv;
      }
    }
  }
  __syncthreads();
}

__global__ __launch_bounds__(THREADS, 2) void siren_kernel(
    const float* __restrict__ coords, const float* __restrict__ bff,
    const float* __restrict__ biasC, const float* __restrict__ b_out,
    const _Float16* __restrict__ wf, const _Float16* __restrict__ wh,
    const _Float16* __restrict__ wo, float* __restrict__ out) {
  extern __shared__ _Float16 hb[];  // chunk-major: [64 chunks][128 tok][8]
  const int tid = threadIdx.x;
  const int t0 = blockIdx.x * TOK;

  // ---- Fourier features: chunks q*4+cb (sin), 16+q*4+cb (cos) ----
  {
    const int t = tid & 127;   // token
    const int q = tid >> 7;    // feature octant: proj j in [q*32, q*32+32)
    const float c0 = coords[(t0 + t) * 3 + 0];
    const float c1 = coords[(t0 + t) * 3 + 1];
    const float c2 = coords[(t0 + t) * 3 + 2];
#pragma unroll
    for (int cb = 0; cb < 4; ++cb) {
      f16x8 sv, cv;
#pragma unroll
      for (int e = 0; e < 8; ++e) {
        const int j = q * 32 + cb * 8 + e;
        float r = fmaf(c0, bff[j], fmaf(c1, bff[128 + j], c2 * bff[256 + j]));
        float fr = __builtin_amdgcn_fractf(r);
        sv[e] = (_Float16)__builtin_amdgcn_sinf(fr);
        cv[e] = (_Float16)__builtin_amdgcn_cosf(fr);
      }
      *(f16x8*)&hb[h_elem(q * 4 + cb, t)] = sv;        // lane-linear store
      *(f16x8*)&hb[h_elem(16 + q * 4 + cb, t)] = cv;
    }
  }
  __syncthreads();

  const int lane = tid & 63;
  const int ln31 = lane & 31;      // 32x32: token col / weight row
  const int hl = lane >> 5;        // k-half selector
  const int m0t = (tid >> 6) * 2;  // wave's first 32-feature mtile

  sine_layer<16>(wf, biasC, hb, lane, m0t, hl, ln31);
#pragma unroll 1
  for (int l = 0; l < 5; ++l)
    sine_layer<32>(wh + l * (512 * 512), biasC + 512 + l * 512, hb, lane, m0t,
                   hl, ln31);

  // ---- final linear (16x16x32): out[t][0..2], 16 tokens/wave, 8 waves ----
  {
    const int lr = lane & 15;
    const int lg = lane >> 4;
    const int wave = tid >> 6;
    f32x4 acc = {0.f, 0.f, 0.f, 0.f};
#pragma unroll
    for (int ks = 0; ks < 16; ++ks) {
      f16x8 a = *(const f16x8*)&wo[lr * 512 + ks * 32 + lg * 8];
      f16x8 b = *(const f16x8*)&hb[h_elem(ks * 4 + lg, wave * 16 + lr)];
      acc = __builtin_amdgcn_mfma_f32_16x16x32_f16(a, b, acc, 0, 0, 0);
    }
    if (lg == 0) {  // C rows 0..3 in lanes 0..15; out-feature = reg idx
      const int t = t0 + wave * 16 + lr;
      out[t * 3 + 0] = acc[0] + b_out[0];
      out[t * 3 + 1] = acc[1] + b_out[1];
      out[t * 3 + 2] = acc[2] + b_out[2];
    }
  }
}

extern "C" void kernel_launch(void* const* d_in, const int* in_sizes, int n_in,
                              void* d_out, int out_size, void* d_ws,
                              size_t ws_size, hipStream_t stream) {
  const float* coords = (const float*)d_in[0];
  const float* bff    = (const float*)d_in[1];
  const float* Wf     = (const float*)d_in[2];
  const float* bf     = (const float*)d_in[3];
  const float* Wh     = (const float*)d_in[4];
  const float* bh     = (const float*)d_in[5];
  const float* Wo     = (const float*)d_in[6];
  const float* bo     = (const float*)d_in[7];
  float* out = (float*)d_out;

  _Float16* w16 = (_Float16*)d_ws;
  float* biasC = (float*)(w16 + N3);  // 16B-aligned (N3*2 % 16 == 0)

  convert_weights<<<(N3 + NBIAS + 255) / 256, 256, 0, stream>>>(
      Wf, Wh, Wo, bf, bh, w16, biasC);

  const size_t lds_bytes = 64 * 128 * 8 * sizeof(_Float16);  // 131072
  siren_kernel<<<L_TOTAL / TOK, THREADS, lds_bytes, stream>>>(
      coords, bff, biasC, bo, w16, w16 + N1, w16 + N2, out);
}